// Round 3
// baseline (178.891 us; speedup 1.0000x reference)
//
#include <hip/hip_runtime.h>

// Problem: B=4, C=256, C4=64, N=4096, f32 in/out.
//   Q = Wqk@x; V = Wv@x + b; E = Q^T Q / 8; A = softmax_rows(E); out = V @ A
// Fused: out[c,m] = sum_n (V[c,n]/Z[n]) * exp(E[n,m]),  Z[n] = sum_m exp(E[n,m])
// exp via exp2: Qt stored scaled by sqrt(log2e/8) so MFMA dot = log2e*E.
// Constant shift SHIFT2 (log2 domain) instead of per-row max (safe: max arg ~21.6).

#define CC 256
#define C4C 64
#define NBATCH 4
#define NN 4096
#define QSCALE 0.42466089f   // sqrt(log2(e)/8)
#define SHIFT2 17.0f

typedef _Float16 f16;
typedef _Float16 half8 __attribute__((ext_vector_type(8)));
typedef float floatx4 __attribute__((ext_vector_type(4)));

static __device__ __forceinline__ unsigned pack2(float a, float b) {
  union { f16 h[2]; unsigned u; } p;
  p.h[0] = (f16)a; p.h[1] = (f16)b;
  return p.u;
}

// ---------------- QV: Q/V projections via MFMA ----------------
// grid (128, 4) block 256 (4 waves). Block tile: 128 oc x 32 n, K=C=256.
#define XT_PITCH 264
__global__ __launch_bounds__(256) void qv_kernel(
    const float* __restrict__ x, const float* __restrict__ Wqk,
    const float* __restrict__ Wv, const float* __restrict__ bv,
    f16* __restrict__ Qt, float* __restrict__ V)
{
  __shared__ __align__(16) f16 xt[32][XT_PITCH];
  const int b = blockIdx.y;
  const int n0 = blockIdx.x * 32;
  const int tid = threadIdx.x;

  // stage x -> LDS transposed (per-thread 8c x 4n register transpose, b128 writes)
  {
    const int nq = tid & 7;
    const int cb = tid >> 3;
    const int c = cb * 8;
    const float* xp = x + (size_t)b * CC * NN + n0 + nq * 4;
    float4 r[8];
#pragma unroll
    for (int j = 0; j < 8; ++j)
      r[j] = *(const float4*)(xp + (size_t)(c + j) * NN);
#pragma unroll
    for (int s = 0; s < 4; ++s) {
      half8 h;
#pragma unroll
      for (int j = 0; j < 8; ++j) h[j] = (f16)(((const float*)&r[j])[s]);
      *(half8*)(&xt[nq * 4 + s][c]) = h;
    }
  }

  const int w = tid >> 6, l = tid & 63, lr = l & 15, lg = l >> 4;
  const float* Wsrc = (w < 2) ? Wqk : Wv;
  const int ocb = (w & 1) * 32;
  half8 af[2][8];
#pragma unroll
  for (int t = 0; t < 2; ++t) {
    const float* wp = Wsrc + (size_t)(ocb + t * 16 + lr) * CC + 8 * lg;
#pragma unroll
    for (int kk = 0; kk < 8; ++kk) {
      float4 wa = *(const float4*)(wp + kk * 32);
      float4 wb = *(const float4*)(wp + kk * 32 + 4);
      half8 h;
      h[0] = (f16)wa.x; h[1] = (f16)wa.y; h[2] = (f16)wa.z; h[3] = (f16)wa.w;
      h[4] = (f16)wb.x; h[5] = (f16)wb.y; h[6] = (f16)wb.z; h[7] = (f16)wb.w;
      af[t][kk] = h;
    }
  }

  __syncthreads();

  floatx4 acc[2][2] = {{{0.f,0.f,0.f,0.f},{0.f,0.f,0.f,0.f}},
                       {{0.f,0.f,0.f,0.f},{0.f,0.f,0.f,0.f}}};
#pragma unroll
  for (int nt = 0; nt < 2; ++nt) {
#pragma unroll
    for (int kk = 0; kk < 8; ++kk) {
      half8 bf = *(const half8*)(&xt[nt * 16 + lr][kk * 32 + 8 * lg]);
      acc[0][nt] = __builtin_amdgcn_mfma_f32_16x16x32_f16(af[0][kk], bf, acc[0][nt], 0, 0, 0);
      acc[1][nt] = __builtin_amdgcn_mfma_f32_16x16x32_f16(af[1][kk], bf, acc[1][nt], 0, 0, 0);
    }
  }

  if (w < 2) {
#pragma unroll
    for (int t = 0; t < 2; ++t)
#pragma unroll
      for (int nt = 0; nt < 2; ++nt) {
        int n = n0 + nt * 16 + lr;
        int oc = w * 32 + t * 16 + 4 * lg;
        union { f16 h[4]; unsigned long long u; } q4;
#pragma unroll
        for (int i = 0; i < 4; ++i) q4.h[i] = (f16)(acc[t][nt][i] * QSCALE);
        *(unsigned long long*)(Qt + ((size_t)(b * NN) + n) * 64 + oc) = q4.u;
      }
  } else {
#pragma unroll
    for (int t = 0; t < 2; ++t)
#pragma unroll
      for (int nt = 0; nt < 2; ++nt) {
        int n = n0 + nt * 16 + lr;
        int oc = (w - 2) * 32 + t * 16 + 4 * lg;
#pragma unroll
        for (int i = 0; i < 4; ++i)
          V[((size_t)(b * C4C) + oc + i) * NN + n] = acc[t][nt][i] + bv[oc + i];
      }
  }
}

// ---------------- Z pass: Zp[mc][b][n] = sum_{m in chunk} exp2(dot2 - SHIFT2) ----
// grid (64, 4, 8) block 256 (4 waves) -> 8 blocks/CU, 100% occupancy.
// No atomics: per-chunk partials, reduced in zr_kernel (fixed order, deterministic).
__global__ __launch_bounds__(256) void z_kernel(
    const f16* __restrict__ Qt, float* __restrict__ Zp)
{
  const int b = blockIdx.y;
  const int n0 = blockIdx.x * 64;
  const int mc = blockIdx.z;
  const int tid = threadIdx.x;
  const int w = tid >> 6;
  const int l = tid & 63;
  const int lr = l & 15, lg = l >> 4;
  const f16* Qb = Qt + (size_t)b * NN * 64;

  const f16* ap = Qb + ((size_t)(n0 + 16 * w + lr)) * 64 + 8 * lg;
  half8 a0 = *(const half8*)(ap);
  half8 a1 = *(const half8*)(ap + 32);

  float rs[4] = {0.f, 0.f, 0.f, 0.f};
  const int mbeg = mc * 512;
  for (int m0 = mbeg; m0 < mbeg + 512; m0 += 64) {
#pragma unroll
    for (int t = 0; t < 4; ++t) {
      const f16* bp = Qb + ((size_t)(m0 + 16 * t + lr)) * 64 + 8 * lg;
      half8 b0 = *(const half8*)(bp);
      half8 b1 = *(const half8*)(bp + 32);
      floatx4 d = {0.f, 0.f, 0.f, 0.f};
      d = __builtin_amdgcn_mfma_f32_16x16x32_f16(a0, b0, d, 0, 0, 0);
      d = __builtin_amdgcn_mfma_f32_16x16x32_f16(a1, b1, d, 0, 0, 0);
#pragma unroll
      for (int i = 0; i < 4; ++i) rs[i] += exp2f(d[i] - SHIFT2);
    }
  }
#pragma unroll
  for (int i = 0; i < 4; ++i) {
    float v = rs[i];
    v += __shfl_xor(v, 1); v += __shfl_xor(v, 2);
    v += __shfl_xor(v, 4); v += __shfl_xor(v, 8);
    rs[i] = v;
  }
  if (lr == 0) {
#pragma unroll
    for (int i = 0; i < 4; ++i) {
      int n = n0 + 16 * w + 4 * lg + i;
      Zp[(size_t)mc * NBATCH * NN + b * NN + n] = rs[i];
    }
  }
}

// ---------------- Z reduce: Z[i] = sum_k Zp[k][i] (fixed order) ----------------
__global__ __launch_bounds__(256) void zr_kernel(
    const float* __restrict__ Zp, float* __restrict__ Z)
{
  int i = blockIdx.x * 256 + threadIdx.x;   // 4*4096 = 16384
  float s = 0.f;
#pragma unroll
  for (int k = 0; k < 8; ++k) s += Zp[(size_t)k * NBATCH * NN + i];
  Z[i] = s;
}

// ---------------- U: U[c,n] = V[c,n] / Z[n]  (fp16) ----------------
__global__ __launch_bounds__(256) void u_kernel(
    const float* __restrict__ V, const float* __restrict__ Z,
    f16* __restrict__ U)
{
  size_t i = (size_t)blockIdx.x * 256 + threadIdx.x; // 1M
  int n = (int)(i & (NN - 1));
  int b = (int)(i >> 18);
  float z = Z[b * NN + n];
  U[i] = (f16)(V[i] / z);
}

// ---------------- PV pass: out[c,m] += sum_n U[c,n]*exp2(dot2-SHIFT2) ----------------
// grid (128, 4, 2) block 512 (8 waves) -> 4 blocks/CU = 100% occupancy.
// Block: 32 m-cols, n-half 2048, step 128. E phase: wave w rows n0+16w..+16 x 32 m.
// PV: wave (wc=w&3, wm=w>>2): c-strip 16*wc, m-strip 16*wm, K=128.
__global__ __launch_bounds__(512, 4) void av_kernel(
    const f16* __restrict__ Qt, const f16* __restrict__ U,
    float* __restrict__ Out)
{
  __shared__ __align__(16) f16 PT[32][136];  // [m_local][n_local], 272B pitch

  const int b = blockIdx.y;
  const int m0 = blockIdx.x * 32;
  const int nbase = blockIdx.z * 2048;
  const int tid = threadIdx.x;
  const int w = tid >> 6;
  const int l = tid & 63;
  const int lr = l & 15, lg = l >> 4;
  const int wc = w & 3, wm = w >> 2;

  const f16* Qb = Qt + (size_t)b * NN * 64;
  const f16* Ub = U + (size_t)b * C4C * NN;

  // hoisted E B-frags for this m-tile (2 x 16 m)
  half8 bq[2][2];
#pragma unroll
  for (int t = 0; t < 2; ++t) {
    const f16* bp = Qb + ((size_t)(m0 + 16 * t + lr)) * 64 + 8 * lg;
    bq[t][0] = *(const half8*)(bp);
    bq[t][1] = *(const half8*)(bp + 32);
  }

  floatx4 o = {0.f, 0.f, 0.f, 0.f};

  for (int n0 = nbase; n0 < nbase + 2048; n0 += 128) {
    // ---- E phase ----
    const f16* ap = Qb + ((size_t)(n0 + 16 * w + lr)) * 64 + 8 * lg;
    half8 a0 = *(const half8*)(ap);
    half8 a1 = *(const half8*)(ap + 32);
    __syncthreads();
#pragma unroll
    for (int t = 0; t < 2; ++t) {
      floatx4 d = {0.f, 0.f, 0.f, 0.f};
      d = __builtin_amdgcn_mfma_f32_16x16x32_f16(a0, bq[t][0], d, 0, 0, 0);
      d = __builtin_amdgcn_mfma_f32_16x16x32_f16(a1, bq[t][1], d, 0, 0, 0);
      unsigned p01 = pack2(exp2f(d[0] - SHIFT2), exp2f(d[1] - SHIFT2));
      unsigned p23 = pack2(exp2f(d[2] - SHIFT2), exp2f(d[3] - SHIFT2));
      int ml = 16 * t + lr;
      int r0 = 16 * w + 4 * lg;
      *(uint2*)(&PT[ml][r0]) = make_uint2(p01, p23);
    }
    __syncthreads();
    // ---- PV phase: K = 128 local n ----
#pragma unroll
    for (int kk = 0; kk < 4; ++kk) {
      half8 u = *(const half8*)(Ub + ((size_t)(16 * wc + lr)) * NN
                                + n0 + kk * 32 + 8 * lg);
      half8 p = *(const half8*)(&PT[16 * wm + lr][kk * 32 + 8 * lg]);
      o = __builtin_amdgcn_mfma_f32_16x16x32_f16(u, p, o, 0, 0, 0);
    }
  }
  // 2 commutative atomic adds (nbase halves) -> deterministic
  {
    int m = m0 + 16 * wm + lr;
#pragma unroll
    for (int i = 0; i < 4; ++i) {
      int c = 16 * wc + 4 * lg + i;
      atomicAdd(&Out[((size_t)b * C4C + c) * NN + m], o[i]);
    }
  }
}

// ---------------- launch ----------------
// ws layout (~8.45 MB, Zp aliased over U region — dead before U is written):
//   Qt  f16 [4][4096][64]   2 MiB    @ 0
//   V   f32 [4][64][4096]   4 MiB    @ 2 MiB
//   Z   f32 [4][4096]       64 KiB   @ 6 MiB
//   U   f16 [4][64][4096]   2 MiB    @ 6 MiB + 64 KiB
//   Zp  f32 [8][4][4096]    512 KiB  @ 6 MiB + 64 KiB (aliases U; Zp dead before u_kernel)
extern "C" void kernel_launch(void* const* d_in, const int* in_sizes, int n_in,
                              void* d_out, int out_size, void* d_ws, size_t ws_size,
                              hipStream_t stream)
{
  const float* x   = (const float*)d_in[0];
  const float* Wqk = (const float*)d_in[1];
  const float* Wv  = (const float*)d_in[2];
  const float* bv  = (const float*)d_in[3];
  float* out = (float*)d_out;

  char* ws = (char*)d_ws;
  f16*   Qt = (f16*)(ws);
  float* V  = (float*)(ws + (2u << 20));
  float* Z  = (float*)(ws + (6u << 20));
  f16*   U  = (f16*)(ws + (6u << 20) + (64u << 10));
  float* Zp = (float*)(ws + (6u << 20) + (64u << 10));  // alias: dead before U written

  hipMemsetAsync(out, 0, (size_t)out_size * sizeof(float), stream);

  qv_kernel<<<dim3(128, 4), 256, 0, stream>>>(x, Wqk, Wv, bv, Qt, V);
  z_kernel<<<dim3(64, 4, 8), 256, 0, stream>>>(Qt, Zp);
  zr_kernel<<<dim3(64), 256, 0, stream>>>(Zp, Z);
  u_kernel<<<dim3(4096), 256, 0, stream>>>(V, Z, U);
  av_kernel<<<dim3(128, 4, 2), 512, 0, stream>>>(Qt, U, out);
}

// Round 4
// 140.476 us; speedup vs baseline: 1.2735x; 1.2735x over previous
//
#include <hip/hip_runtime.h>

// Problem: B=4, C=256, C4=64, N=4096, f32 in/out.
//   Q = Wqk@x; V = Wv@x + b; E = Q^T Q / 8; A = softmax_rows(E); out = V @ A
// Fused: out[c,m] = sum_n (V[c,n]/Z[n]) * exp(E[n,m]),  Z[n] = sum_m exp(E[n,m])
// exp via exp2: Qt stored scaled by sqrt(log2e/8) so MFMA dot = log2e*E.
// Constant shift SHIFT2 (log2 domain) instead of per-row max (safe: max arg ~21.6).
// av pass: P stays IN REGISTERS — E-MFMA D-layout == PV B-frag layout for
// mfma_f32_16x16x16f16 (D: row=4*lg+i, col=lr;  B: k=4*lg+j, col=lr).

#define CC 256
#define C4C 64
#define NBATCH 4
#define NN 4096
#define QSCALE 0.42466089f   // sqrt(log2(e)/8)
#define SHIFT2 17.0f

typedef _Float16 f16;
typedef _Float16 half4 __attribute__((ext_vector_type(4)));
typedef _Float16 half8 __attribute__((ext_vector_type(8)));
typedef float floatx4 __attribute__((ext_vector_type(4)));

// ---------------- QV: Q/V projections via MFMA ----------------
// grid (128, 4) block 256 (4 waves). Block tile: 128 oc x 32 n, K=C=256.
#define XT_PITCH 264
__global__ __launch_bounds__(256) void qv_kernel(
    const float* __restrict__ x, const float* __restrict__ Wqk,
    const float* __restrict__ Wv, const float* __restrict__ bv,
    f16* __restrict__ Qt, float* __restrict__ V)
{
  __shared__ __align__(16) f16 xt[32][XT_PITCH];
  const int b = blockIdx.y;
  const int n0 = blockIdx.x * 32;
  const int tid = threadIdx.x;

  // stage x -> LDS transposed (per-thread 8c x 4n register transpose, b128 writes)
  {
    const int nq = tid & 7;
    const int cb = tid >> 3;
    const int c = cb * 8;
    const float* xp = x + (size_t)b * CC * NN + n0 + nq * 4;
    float4 r[8];
#pragma unroll
    for (int j = 0; j < 8; ++j)
      r[j] = *(const float4*)(xp + (size_t)(c + j) * NN);
#pragma unroll
    for (int s = 0; s < 4; ++s) {
      half8 h;
#pragma unroll
      for (int j = 0; j < 8; ++j) h[j] = (f16)(((const float*)&r[j])[s]);
      *(half8*)(&xt[nq * 4 + s][c]) = h;
    }
  }

  const int w = tid >> 6, l = tid & 63, lr = l & 15, lg = l >> 4;
  const float* Wsrc = (w < 2) ? Wqk : Wv;
  const int ocb = (w & 1) * 32;
  half8 af[2][8];
#pragma unroll
  for (int t = 0; t < 2; ++t) {
    const float* wp = Wsrc + (size_t)(ocb + t * 16 + lr) * CC + 8 * lg;
#pragma unroll
    for (int kk = 0; kk < 8; ++kk) {
      float4 wa = *(const float4*)(wp + kk * 32);
      float4 wb = *(const float4*)(wp + kk * 32 + 4);
      half8 h;
      h[0] = (f16)wa.x; h[1] = (f16)wa.y; h[2] = (f16)wa.z; h[3] = (f16)wa.w;
      h[4] = (f16)wb.x; h[5] = (f16)wb.y; h[6] = (f16)wb.z; h[7] = (f16)wb.w;
      af[t][kk] = h;
    }
  }

  __syncthreads();

  floatx4 acc[2][2] = {{{0.f,0.f,0.f,0.f},{0.f,0.f,0.f,0.f}},
                       {{0.f,0.f,0.f,0.f},{0.f,0.f,0.f,0.f}}};
#pragma unroll
  for (int nt = 0; nt < 2; ++nt) {
#pragma unroll
    for (int kk = 0; kk < 8; ++kk) {
      half8 bf = *(const half8*)(&xt[nt * 16 + lr][kk * 32 + 8 * lg]);
      acc[0][nt] = __builtin_amdgcn_mfma_f32_16x16x32_f16(af[0][kk], bf, acc[0][nt], 0, 0, 0);
      acc[1][nt] = __builtin_amdgcn_mfma_f32_16x16x32_f16(af[1][kk], bf, acc[1][nt], 0, 0, 0);
    }
  }

  if (w < 2) {
#pragma unroll
    for (int t = 0; t < 2; ++t)
#pragma unroll
      for (int nt = 0; nt < 2; ++nt) {
        int n = n0 + nt * 16 + lr;
        int oc = w * 32 + t * 16 + 4 * lg;
        union { f16 h[4]; unsigned long long u; } q4;
#pragma unroll
        for (int i = 0; i < 4; ++i) q4.h[i] = (f16)(acc[t][nt][i] * QSCALE);
        *(unsigned long long*)(Qt + ((size_t)(b * NN) + n) * 64 + oc) = q4.u;
      }
  } else {
#pragma unroll
    for (int t = 0; t < 2; ++t)
#pragma unroll
      for (int nt = 0; nt < 2; ++nt) {
        int n = n0 + nt * 16 + lr;
        int oc = (w - 2) * 32 + t * 16 + 4 * lg;
#pragma unroll
        for (int i = 0; i < 4; ++i)
          V[((size_t)(b * C4C) + oc + i) * NN + n] = acc[t][nt][i] + bv[oc + i];
      }
  }
}

// ---------------- Z pass: Zp[mc][b][n] = sum_{m in chunk} exp2(dot2 - SHIFT2) ----
// grid (64, 4, 8) block 256 (4 waves) -> 8 blocks/CU.
__global__ __launch_bounds__(256) void z_kernel(
    const f16* __restrict__ Qt, float* __restrict__ Zp)
{
  const int b = blockIdx.y;
  const int n0 = blockIdx.x * 64;
  const int mc = blockIdx.z;
  const int tid = threadIdx.x;
  const int w = tid >> 6;
  const int l = tid & 63;
  const int lr = l & 15, lg = l >> 4;
  const f16* Qb = Qt + (size_t)b * NN * 64;

  const f16* ap = Qb + ((size_t)(n0 + 16 * w + lr)) * 64 + 8 * lg;
  half8 a0 = *(const half8*)(ap);
  half8 a1 = *(const half8*)(ap + 32);

  float rs[4] = {0.f, 0.f, 0.f, 0.f};
  const int mbeg = mc * 512;
  for (int m0 = mbeg; m0 < mbeg + 512; m0 += 64) {
#pragma unroll
    for (int t = 0; t < 4; ++t) {
      const f16* bp = Qb + ((size_t)(m0 + 16 * t + lr)) * 64 + 8 * lg;
      half8 b0 = *(const half8*)(bp);
      half8 b1 = *(const half8*)(bp + 32);
      floatx4 d = {0.f, 0.f, 0.f, 0.f};
      d = __builtin_amdgcn_mfma_f32_16x16x32_f16(a0, b0, d, 0, 0, 0);
      d = __builtin_amdgcn_mfma_f32_16x16x32_f16(a1, b1, d, 0, 0, 0);
#pragma unroll
      for (int i = 0; i < 4; ++i) rs[i] += exp2f(d[i] - SHIFT2);
    }
  }
#pragma unroll
  for (int i = 0; i < 4; ++i) {
    float v = rs[i];
    v += __shfl_xor(v, 1); v += __shfl_xor(v, 2);
    v += __shfl_xor(v, 4); v += __shfl_xor(v, 8);
    rs[i] = v;
  }
  if (lr == 0) {
#pragma unroll
    for (int i = 0; i < 4; ++i) {
      int n = n0 + 16 * w + 4 * lg + i;
      Zp[(size_t)mc * NBATCH * NN + b * NN + n] = rs[i];
    }
  }
}

// ---------------- Z reduce: Z[i] = sum_k Zp[k][i] (fixed order) ----------------
__global__ __launch_bounds__(256) void zr_kernel(
    const float* __restrict__ Zp, float* __restrict__ Z)
{
  int i = blockIdx.x * 256 + threadIdx.x;   // 4*4096 = 16384
  float s = 0.f;
#pragma unroll
  for (int k = 0; k < 8; ++k) s += Zp[(size_t)k * NBATCH * NN + i];
  Z[i] = s;
}

// ---------------- U: U[c,n] = V[c,n] / Z[n]  (fp16) ----------------
__global__ __launch_bounds__(256) void u_kernel(
    const float* __restrict__ V, const float* __restrict__ Z,
    f16* __restrict__ U)
{
  size_t i = (size_t)blockIdx.x * 256 + threadIdx.x; // 1M
  int n = (int)(i & (NN - 1));
  int b = (int)(i >> 18);
  float z = Z[b * NN + n];
  U[i] = (f16)(V[i] / z);
}

// ---------------- PV pass, barrier-free ----------------
// grid (64, 4) block 512 (8 waves), 1 block/CU. Block: 64 m-cols, ALL 4096 n.
// Per iter (128 n): wave w owns n-strip ns = it*128 + 16w.
//   E: A = Qt[ns..ns+16) rows, B = hoisted m-tile frags -> D = P[n(4lg+i)][m(lr)]
//   exp2 -> f16 in-register -> directly the B-frag of mfma_f32_16x16x16f16
//   PV: A = U[16cs+lr][ns+4lg..+4), K=16 = wave's own strip. No LDS, no barriers.
// End: fixed-order cross-wave LDS reduction (deterministic, no atomics).
__global__ __launch_bounds__(512, 2) void av_kernel(
    const f16* __restrict__ Qt, const f16* __restrict__ U,
    float* __restrict__ Out)
{
  __shared__ __align__(16) float red[8][4][16][16];  // [w][t][r][lr], 32 KB

  const int b = blockIdx.y;
  const int m0 = blockIdx.x * 64;
  const int tid = threadIdx.x;
  const int w = tid >> 6;
  const int l = tid & 63;
  const int lr = l & 15, lg = l >> 4;

  const f16* Qb = Qt + (size_t)b * NN * 64;
  const f16* Ub = U + (size_t)b * C4C * NN;

  // hoisted E B-frags for the 64-m tile
  half8 bq[4][2];
#pragma unroll
  for (int t = 0; t < 4; ++t) {
    const f16* bp = Qb + ((size_t)(m0 + 16 * t + lr)) * 64 + 8 * lg;
    bq[t][0] = *(const half8*)(bp);
    bq[t][1] = *(const half8*)(bp + 32);
  }

  floatx4 o[4][4];
#pragma unroll
  for (int cs = 0; cs < 4; ++cs)
#pragma unroll
    for (int t = 0; t < 4; ++t) o[cs][t] = (floatx4){0.f, 0.f, 0.f, 0.f};

#pragma unroll 2
  for (int it = 0; it < 32; ++it) {
    const int ns = it * 128 + 16 * w;            // this wave's n-strip
    const f16* ap = Qb + ((size_t)(ns + lr)) * 64 + 8 * lg;
    half8 a0 = *(const half8*)(ap);
    half8 a1 = *(const half8*)(ap + 32);
    half4 ua[4];
#pragma unroll
    for (int cs = 0; cs < 4; ++cs)
      ua[cs] = *(const half4*)(Ub + ((size_t)(16 * cs + lr)) * NN + ns + 4 * lg);

#pragma unroll
    for (int t = 0; t < 4; ++t) {
      floatx4 d = {0.f, 0.f, 0.f, 0.f};
      d = __builtin_amdgcn_mfma_f32_16x16x32_f16(a0, bq[t][0], d, 0, 0, 0);
      d = __builtin_amdgcn_mfma_f32_16x16x32_f16(a1, bq[t][1], d, 0, 0, 0);
      half4 bt;
#pragma unroll
      for (int i = 0; i < 4; ++i) bt[i] = (f16)exp2f(d[i] - SHIFT2);
#pragma unroll
      for (int cs = 0; cs < 4; ++cs)
        o[cs][t] = __builtin_amdgcn_mfma_f32_16x16x16f16(ua[cs], bt, o[cs][t], 0, 0, 0);
    }
  }

  // ---- cross-wave reduction, fixed order: deterministic, no atomics ----
#pragma unroll 1
  for (int cs = 0; cs < 4; ++cs) {
    __syncthreads();   // red free (round 1: nothing pending; else: prior reads done)
#pragma unroll
    for (int t = 0; t < 4; ++t)
#pragma unroll
      for (int i = 0; i < 4; ++i)
        red[w][t][4 * lg + i][lr] = o[cs][t][i];
    __syncthreads();
    const int r = tid >> 5;              // 0..15
    const int m = (tid * 2) & 63;        // even
    const int t = m >> 4, c0 = m & 15;
    float2 s = {0.f, 0.f};
#pragma unroll
    for (int ww = 0; ww < 8; ++ww) {
      s.x += red[ww][t][r][c0];
      s.y += red[ww][t][r][c0 + 1];
    }
    *(float2*)(&Out[((size_t)b * C4C + cs * 16 + r) * NN + m0 + m]) = s;
  }
}

// ---------------- launch ----------------
// ws layout (~8.45 MB, Zp aliased over U region — dead before U is written):
//   Qt  f16 [4][4096][64]   2 MiB    @ 0
//   V   f32 [4][64][4096]   4 MiB    @ 2 MiB
//   Z   f32 [4][4096]       64 KiB   @ 6 MiB
//   U   f16 [4][64][4096]   2 MiB    @ 6 MiB + 64 KiB
//   Zp  f32 [8][4][4096]    512 KiB  @ 6 MiB + 64 KiB (aliases U; Zp dead before u_kernel)
extern "C" void kernel_launch(void* const* d_in, const int* in_sizes, int n_in,
                              void* d_out, int out_size, void* d_ws, size_t ws_size,
                              hipStream_t stream)
{
  const float* x   = (const float*)d_in[0];
  const float* Wqk = (const float*)d_in[1];
  const float* Wv  = (const float*)d_in[2];
  const float* bv  = (const float*)d_in[3];
  float* out = (float*)d_out;

  char* ws = (char*)d_ws;
  f16*   Qt = (f16*)(ws);
  float* V  = (float*)(ws + (2u << 20));
  float* Z  = (float*)(ws + (6u << 20));
  f16*   U  = (f16*)(ws + (6u << 20) + (64u << 10));
  float* Zp = (float*)(ws + (6u << 20) + (64u << 10));  // alias: dead before U written

  qv_kernel<<<dim3(128, 4), 256, 0, stream>>>(x, Wqk, Wv, bv, Qt, V);
  z_kernel<<<dim3(64, 4, 8), 256, 0, stream>>>(Qt, Zp);
  zr_kernel<<<dim3(64), 256, 0, stream>>>(Zp, Z);
  u_kernel<<<dim3(4096), 256, 0, stream>>>(V, Z, U);
  av_kernel<<<dim3(64, 4), 512, 0, stream>>>(Qt, U, out);
}